// Round 10
// baseline (104.126 us; speedup 1.0000x reference)
//
#include <hip/hip_runtime.h>
#include <hip/hip_bf16.h>
#include <stdint.h>

// B=4, C=64, N=16384, K=16, CO=64 (fp32 I/O, int32 idx)
// R10 = R8 + k2 gather width doubled (dwordx2, 4 rows/instruction):
//  r4=lane>>4 row-in-quad, c4=lane&15 channel-quad (ch 4c4..4c4+3).
//  Gather instrs 64->32/wave (same cachelines in flight = same MLP,
//  half the issue slots). Index machinery = R8's proven vector-load +
//  ds_bpermute (no R1-style select chains -> no spill: ~70 live VGPR).
//  y1 loads and hselp stores become uint2 (half count). Per-row channel
//  sums bit-identical (same k order); only cross-row stat regrouping
//  changes (ulp-level, threshold 0.113).
// Attribution: k1<=7.7us, k2~13us (issue-count-bound: VALU cuts R7 and
// occupancy R9 both neutral), k3<=3.9us; ~77us harness fixed.
#define NDIM 16384
#define KNB 16
#define BNK_F 1048576.0f

typedef __attribute__((ext_vector_type(8))) short bf16x8_t;
typedef __attribute__((ext_vector_type(4))) float f32x4_t;
typedef __attribute__((ext_vector_type(2))) float f32x2_t;

__device__ inline unsigned pack_bf16(float a, float b) {
    return (unsigned)__bfloat16_as_ushort(__float2bfloat16(a))
         | ((unsigned)__bfloat16_as_ushort(__float2bfloat16(b)) << 16);
}

__device__ inline float wave_red16_32(float v) {
    v += __shfl_xor(v, 16);
    v += __shfl_xor(v, 32);
    return v;
}

// ---------------- Kernel 1: MFMA GEMM (R7-proven, unchanged) ----------------
__global__ __launch_bounds__(256) void gemm_mfma_kernel(
    const float* __restrict__ x,            // (B, 64, N)
    const float* __restrict__ W,            // (64, 128)
    unsigned* __restrict__ y1p,             // (B,N,32) bf16-pairs
    unsigned* __restrict__ y2p,             // (B,N,32) bf16-pairs
    float* __restrict__ statsN)             // (32,128) striped stats - zeroed here
{
    __shared__ alignas(16) short lds_a[128 * 72];  // row pad 72 -> 2-way-free b128
    __shared__ alignas(16) short lds_b[64 * 72];   // x tile, n-major

    const int tid = threadIdx.x;
    if (blockIdx.x == 0) {
        for (int i = tid; i < 4096; i += 256) statsN[i] = 0.0f;
    }
    const int b  = blockIdx.x >> 8;
    const int n0 = (blockIdx.x & 255) << 6;

    for (int idx = tid; idx < 1024; idx += 256) {
        const int r = idx >> 4, q = idx & 15;
        const f32x4_t wa = *(const f32x4_t*)&W[r * 128 + q * 4];
        const f32x4_t wb = *(const f32x4_t*)&W[r * 128 + 64 + q * 4];
        const f32x4_t wsum = wa + wb;                  // v_pk_add_f32
        uint2 pa = { pack_bf16(wsum[0], wsum[1]), pack_bf16(wsum[2], wsum[3]) };
        uint2 pb = { pack_bf16(wb[0], wb[1]),     pack_bf16(wb[2], wb[3]) };
        *(uint2*)&lds_a[r * 72 + q * 4]        = pa;
        *(uint2*)&lds_a[(64 + r) * 72 + q * 4] = pb;
    }
    {
        const float* xb = x + (size_t)b * 64 * NDIM + n0;
        const int n = tid & 63;
        unsigned* lb32 = (unsigned*)lds_b;
        for (int cp = tid >> 6; cp < 32; cp += 4) {
            int c = cp * 2;
            float x0 = xb[(size_t)c * NDIM + n];
            float x1 = xb[(size_t)(c + 1) * NDIM + n];
            lb32[n * 36 + cp] = pack_bf16(x0, x1);
        }
    }
    __syncthreads();

    const int lane = tid & 63;
    const int w    = tid >> 6;
    const int m    = lane & 15;
    const int q    = lane >> 4;
    const int n    = w * 16 + m;

    const bf16x8_t b0 = *(const bf16x8_t*)&lds_b[n * 72 + q * 8];
    const bf16x8_t b1 = *(const bf16x8_t*)&lds_b[n * 72 + q * 8 + 32];

    const size_t rowbase = ((size_t)(b * NDIM + n0 + n)) * 32;
    #pragma unroll
    for (int t = 0; t < 8; ++t) {
        const short* ap = &lds_a[(t * 16 + m) * 72 + q * 8];
        bf16x8_t a0 = *(const bf16x8_t*)ap;
        bf16x8_t a1 = *(const bf16x8_t*)(ap + 32);
        f32x4_t acc = {0.f, 0.f, 0.f, 0.f};
        acc = __builtin_amdgcn_mfma_f32_16x16x32_bf16(a0, b0, acc, 0, 0, 0);
        acc = __builtin_amdgcn_mfma_f32_16x16x32_bf16(a1, b1, acc, 0, 0, 0);
        unsigned* dst = (t < 4) ? y1p : y2p;
        uint2 pk = { pack_bf16(acc[0], acc[1]), pack_bf16(acc[2], acc[3]) };
        *(uint2*)&dst[rowbase + (t & 3) * 8 + q * 2] = pk;
    }
}

// ---------------- Kernel 2: gather, dwordx2 / 4 rows per instruction ----------------
// 2048 blocks x 256, XCD-pinned batches. 16 dwordx2 gathers in flight/wave
// (same 128 cachelines as R8's 32 dword gathers; half the instructions).
__global__ __launch_bounds__(256, 4) void gather_kernel(
    const unsigned* __restrict__ y1p,        // (B,N,32) bf16-pairs
    const unsigned* __restrict__ y2p,
    const int* __restrict__ ei,              // (B, N, 16)
    const float* __restrict__ gamma,
    unsigned* __restrict__ hselp,            // (B,N,32) bf16-pairs
    float* __restrict__ statsN)              // (32,128)
{
    const int tid  = threadIdx.x;
    const int w    = __builtin_amdgcn_readfirstlane(tid >> 6);
    const int lane = tid & 63;
    const int r4   = lane >> 4;              // row-in-quad 0..3
    const int c4   = lane & 15;              // channels 4c4..4c4+3
    const int g    = blockIdx.x;
    const int xcd  = g & 7;
    const int b    = xcd >> 1;
    const int row0 = b * NDIM + (xcd & 1) * 8192 + (g >> 3) * 32 + w * 8;

    // 128 wave indices: 2 coalesced loads (R8-proven)
    const int idx0 = ei[(size_t)row0 * KNB + lane];        // rows row0..row0+3
    const int idx1 = ei[(size_t)row0 * KNB + 64 + lane];   // rows row0+4..row0+7
    // y1 prefetch: this lane's two rows, uint2 (pairs 2c4, 2c4+1)
    const uint2 y1A = *(const uint2*)&y1p[(size_t)(row0 + r4) * 32 + c4 * 2];
    const uint2 y1B = *(const uint2*)&y1p[(size_t)(row0 + 4 + r4) * 32 + c4 * 2];

    const f32x4_t gv = *(const f32x4_t*)&gamma[c4 * 4];
    const unsigned sgn0 = (gv[0] >= 0.0f) ? 0x80000000u : 0u;
    const unsigned sgn1 = (gv[1] >= 0.0f) ? 0x80000000u : 0u;
    const unsigned sgn2 = (gv[2] >= 0.0f) ? 0x80000000u : 0u;
    const unsigned sgn3 = (gv[3] >= 0.0f) ? 0x80000000u : 0u;

    const char* y2base = (const char*)y2p + (size_t)b * NDIM * 128;
    const unsigned coff = (unsigned)(c4 << 3);   // byte off of pair 2c4
    const int vb = (lane & 48) << 2;             // bpermute base = r4*64 bytes

    f32x2_t ssumA = {0.f, 0.f}, ssumB = {0.f, 0.f};
    f32x2_t ssqA  = {0.f, 0.f}, ssqB  = {0.f, 0.f};

    #pragma unroll
    for (int t = 0; t < 2; ++t) {
        const int srci = t ? idx1 : idx0;
        const int row  = row0 + t * 4 + r4;
        const uint2 y1u = t ? y1B : y1A;

        uint2 u[KNB];
        #pragma unroll
        for (int k = 0; k < KNB; ++k) {
            // row (row0+t*4+r4)'s index k lives in lane r4*16+k of srci
            int j = __builtin_amdgcn_ds_bpermute(vb + 4 * k, srci);
            u[k] = *(const uint2*)(y2base + ((((unsigned)j) << 7) + coff));
        }

        f32x2_t sA = {0.f, 0.f}, sB = {0.f, 0.f};
        f32x2_t qA = {0.f, 0.f}, qB = {0.f, 0.f};
        float M0 = -3.402823e38f, M1 = -3.402823e38f;
        float M2 = -3.402823e38f, M3 = -3.402823e38f;
        #pragma unroll
        for (int k = 0; k < KNB; k += 2) {
            unsigned xa = u[k].x,     ya = u[k].y;
            unsigned xb = u[k + 1].x, yb = u[k + 1].y;
            f32x2_t vA0 = { __uint_as_float(xa << 16), __uint_as_float(xa & 0xffff0000u) };
            f32x2_t vB0 = { __uint_as_float(ya << 16), __uint_as_float(ya & 0xffff0000u) };
            f32x2_t vA1 = { __uint_as_float(xb << 16), __uint_as_float(xb & 0xffff0000u) };
            f32x2_t vB1 = { __uint_as_float(yb << 16), __uint_as_float(yb & 0xffff0000u) };
            sA += vA0;  qA = __builtin_elementwise_fma(vA0, vA0, qA);
            sA += vA1;  qA = __builtin_elementwise_fma(vA1, vA1, qA);
            sB += vB0;  qB = __builtin_elementwise_fma(vB0, vB0, qB);
            sB += vB1;  qB = __builtin_elementwise_fma(vB1, vB1, qB);
            M0 = fmaxf(fmaxf(M0, __uint_as_float((xa << 16) ^ sgn0)),
                       __uint_as_float((xb << 16) ^ sgn0));          // v_max3_f32
            M1 = fmaxf(fmaxf(M1, __uint_as_float((xa & 0xffff0000u) ^ sgn1)),
                       __uint_as_float((xb & 0xffff0000u) ^ sgn1));
            M2 = fmaxf(fmaxf(M2, __uint_as_float((ya << 16) ^ sgn2)),
                       __uint_as_float((yb << 16) ^ sgn2));
            M3 = fmaxf(fmaxf(M3, __uint_as_float((ya & 0xffff0000u) ^ sgn3)),
                       __uint_as_float((yb & 0xffff0000u) ^ sgn3));
        }

        const f32x2_t y1vA = { __uint_as_float(y1u.x << 16),
                               __uint_as_float(y1u.x & 0xffff0000u) };
        const f32x2_t y1vB = { __uint_as_float(y1u.y << 16),
                               __uint_as_float(y1u.y & 0xffff0000u) };
        const float h0 = y1vA.x - __uint_as_float(__float_as_uint(M0) ^ sgn0);
        const float h1 = y1vA.y - __uint_as_float(__float_as_uint(M1) ^ sgn1);
        const float h2 = y1vB.x - __uint_as_float(__float_as_uint(M2) ^ sgn2);
        const float h3 = y1vB.y - __uint_as_float(__float_as_uint(M3) ^ sgn3);
        uint2 ho = { pack_bf16(h0, h1), pack_bf16(h2, h3) };
        *(uint2*)&hselp[(size_t)row * 32 + c4 * 2] = ho;

        ssumA += (f32x2_t){16.f, 16.f} * y1vA - sA;
        ssumB += (f32x2_t){16.f, 16.f} * y1vB - sB;
        ssqA  += __builtin_elementwise_fma(
                    __builtin_elementwise_fma((f32x2_t){-2.f, -2.f}, sA,
                                              (f32x2_t){16.f, 16.f} * y1vA),
                    y1vA, qA);
        ssqB  += __builtin_elementwise_fma(
                    __builtin_elementwise_fma((f32x2_t){-2.f, -2.f}, sB,
                                              (f32x2_t){16.f, 16.f} * y1vB),
                    y1vB, qB);
    }

    // reduce across the 4 row-quads (lanes ^16, ^32)
    ssumA.x = wave_red16_32(ssumA.x);  ssumA.y = wave_red16_32(ssumA.y);
    ssumB.x = wave_red16_32(ssumB.x);  ssumB.y = wave_red16_32(ssumB.y);
    ssqA.x  = wave_red16_32(ssqA.x);   ssqA.y  = wave_red16_32(ssqA.y);
    ssqB.x  = wave_red16_32(ssqB.x);   ssqB.y  = wave_red16_32(ssqB.y);

    __shared__ float rs[4][64];
    __shared__ float rq[4][64];
    if (r4 == 0) {
        rs[w][c4 * 4 + 0] = ssumA.x;  rs[w][c4 * 4 + 1] = ssumA.y;
        rs[w][c4 * 4 + 2] = ssumB.x;  rs[w][c4 * 4 + 3] = ssumB.y;
        rq[w][c4 * 4 + 0] = ssqA.x;   rq[w][c4 * 4 + 1] = ssqA.y;
        rq[w][c4 * 4 + 2] = ssqB.x;   rq[w][c4 * 4 + 3] = ssqB.y;
    }
    __syncthreads();
    if (tid < 128) {
        const int c = tid & 63;
        float v = 0.f;
        if (tid < 64) { for (int r = 0; r < 4; ++r) v += rs[r][c]; }
        else          { for (int r = 0; r < 4; ++r) v += rq[r][c]; }
        atomicAdd(&statsN[(g & 31) * 128 + tid], v);   // striped: ~64 adds/line
    }
}

// ---------------- Kernel 3: reduce-in-prologue + affine + leaky + transpose ----------------
__global__ __launch_bounds__(256) void out_kernel(
    const unsigned* __restrict__ hselp,      // (B,N,32) bf16-pairs
    const float* __restrict__ statsN,        // (32,128)
    const float* __restrict__ gamma,
    const float* __restrict__ beta,
    float* __restrict__ out)                 // (B, 64, N)
{
    __shared__ float tile[64 * 65];
    __shared__ float colsum[128];
    __shared__ float sc[64], bi[64];
    const int tid = threadIdx.x;

    if (tid < 128) {
        float v = 0.f;
        #pragma unroll
        for (int i = 0; i < 32; ++i) v += statsN[i * 128 + tid];
        colsum[tid] = v;
    }
    __syncthreads();
    if (tid < 64) {
        float mean = colsum[tid] * (1.0f / BNK_F);
        float var  = colsum[64 + tid] * (1.0f / BNK_F) - mean * mean;
        float s    = gamma[tid] * rsqrtf(var + 1e-5f);
        sc[tid] = s;
        bi[tid] = beta[tid] - mean * s;
    }
    __syncthreads();

    const int b  = blockIdx.x >> 8;
    const int n0 = (blockIdx.x & 255) << 6;
    const size_t bn0 = (size_t)b * NDIM + n0;
    const int c4 = tid & 15;

    for (int r = tid >> 4; r < 64; r += 16) {
        uint2 u = *(const uint2*)&hselp[(bn0 + r) * 32 + c4 * 2];
        float v0 = fmaf(sc[4 * c4],     __uint_as_float(u.x << 16),         bi[4 * c4]);
        float v1 = fmaf(sc[4 * c4 + 1], __uint_as_float(u.x & 0xffff0000u), bi[4 * c4 + 1]);
        float v2 = fmaf(sc[4 * c4 + 2], __uint_as_float(u.y << 16),         bi[4 * c4 + 2]);
        float v3 = fmaf(sc[4 * c4 + 3], __uint_as_float(u.y & 0xffff0000u), bi[4 * c4 + 3]);
        v0 = (v0 >= 0.f) ? v0 : 0.2f * v0;
        v1 = (v1 >= 0.f) ? v1 : 0.2f * v1;
        v2 = (v2 >= 0.f) ? v2 : 0.2f * v2;
        v3 = (v3 >= 0.f) ? v3 : 0.2f * v3;
        tile[r * 65 + 4 * c4]     = v0;
        tile[r * 65 + 4 * c4 + 1] = v1;
        tile[r * 65 + 4 * c4 + 2] = v2;
        tile[r * 65 + 4 * c4 + 3] = v3;
    }
    __syncthreads();
    const int ln = tid & 15;
    for (int o = tid >> 4; o < 64; o += 16) {
        f32x4_t v;
        v[0] = tile[(ln * 4 + 0) * 65 + o];
        v[1] = tile[(ln * 4 + 1) * 65 + o];
        v[2] = tile[(ln * 4 + 2) * 65 + o];
        v[3] = tile[(ln * 4 + 3) * 65 + o];
        *(f32x4_t*)&out[((size_t)(b * 64 + o) << 14) + n0 + ln * 4] = v;
    }
}

extern "C" void kernel_launch(void* const* d_in, const int* in_sizes, int n_in,
                              void* d_out, int out_size, void* d_ws, size_t ws_size,
                              hipStream_t stream) {
    const float* x     = (const float*)d_in[0];
    const int*   ei    = (const int*)d_in[1];
    const float* W     = (const float*)d_in[2];
    const float* gamma = (const float*)d_in[3];
    const float* beta  = (const float*)d_in[4];
    float* out = (float*)d_out;

    char* ws = (char*)d_ws;
    unsigned* y1p    = (unsigned*)(ws);                       // 8 MiB (bf16 pairs)
    unsigned* y2p    = (unsigned*)(ws + 8388608);             // 8 MiB
    unsigned* hselp  = (unsigned*)(ws + 16777216);            // 8 MiB
    float*    statsN = (float*)(ws + 25165824);               // 16 KiB (32x128)

    gemm_mfma_kernel <<<dim3(1024), dim3(256), 0, stream>>>(x, W, y1p, y2p, statsN);
    gather_kernel    <<<dim3(2048), dim3(256), 0, stream>>>(y1p, y2p, ei, gamma, hselp, statsN);
    out_kernel       <<<dim3(1024), dim3(256), 0, stream>>>(hselp, statsN, gamma, beta, out);
}

// Round 11
// 102.489 us; speedup vs baseline: 1.0160x; 1.0160x over previous
//
#include <hip/hip_runtime.h>
#include <hip/hip_bf16.h>
#include <stdint.h>

// B=4, C=64, N=16384, K=16, CO=64 (fp32 I/O, int32 idx)
// R11 = revert to R8 (measured champion, 101.88us, absmax 0.03125).
// Evidence ledger for k2 (the only non-floor kernel, ~13us):
//   R7  VALU cut (pk-f32):        neutral
//   R9  occupancy 4->8 blocks/CU: neutral
//   R10 issue count halved (x2):  -2us regression
// -> k2 is L2 cacheline-request-rate bound (1M gathers x 128B rows,
//    semantically required). k1 <=7.7us (near HBM floor), k3 <=3.9us
//    (HBM floor). ~77us of bench dur is harness fixed cost.
// This is the practical ceiling; this round recovers the champion.
#define NDIM 16384
#define KNB 16
#define BNK_F 1048576.0f

typedef __attribute__((ext_vector_type(8))) short bf16x8_t;
typedef __attribute__((ext_vector_type(4))) float f32x4_t;
typedef __attribute__((ext_vector_type(2))) float f32x2_t;

__device__ inline unsigned pack_bf16(float a, float b) {
    return (unsigned)__bfloat16_as_ushort(__float2bfloat16(a))
         | ((unsigned)__bfloat16_as_ushort(__float2bfloat16(b)) << 16);
}

// ---------------- Kernel 1: MFMA GEMM ----------------
__global__ __launch_bounds__(256) void gemm_mfma_kernel(
    const float* __restrict__ x,            // (B, 64, N)
    const float* __restrict__ W,            // (64, 128)
    unsigned* __restrict__ y1p,             // (B,N,32) bf16-pairs
    unsigned* __restrict__ y2p,             // (B,N,32) bf16-pairs
    float* __restrict__ statsN)             // (32,128) striped stats - zeroed here
{
    __shared__ alignas(16) short lds_a[128 * 72];  // row pad 72 -> 2-way-free b128
    __shared__ alignas(16) short lds_b[64 * 72];   // x tile, n-major

    const int tid = threadIdx.x;
    if (blockIdx.x == 0) {
        for (int i = tid; i < 4096; i += 256) statsN[i] = 0.0f;
    }
    const int b  = blockIdx.x >> 8;
    const int n0 = (blockIdx.x & 255) << 6;

    for (int idx = tid; idx < 1024; idx += 256) {
        const int r = idx >> 4, q = idx & 15;
        const f32x4_t wa = *(const f32x4_t*)&W[r * 128 + q * 4];
        const f32x4_t wb = *(const f32x4_t*)&W[r * 128 + 64 + q * 4];
        const f32x4_t wsum = wa + wb;                  // v_pk_add_f32
        uint2 pa = { pack_bf16(wsum[0], wsum[1]), pack_bf16(wsum[2], wsum[3]) };
        uint2 pb = { pack_bf16(wb[0], wb[1]),     pack_bf16(wb[2], wb[3]) };
        *(uint2*)&lds_a[r * 72 + q * 4]        = pa;
        *(uint2*)&lds_a[(64 + r) * 72 + q * 4] = pb;
    }
    {
        const float* xb = x + (size_t)b * 64 * NDIM + n0;
        const int n = tid & 63;
        unsigned* lb32 = (unsigned*)lds_b;
        for (int cp = tid >> 6; cp < 32; cp += 4) {
            int c = cp * 2;
            float x0 = xb[(size_t)c * NDIM + n];
            float x1 = xb[(size_t)(c + 1) * NDIM + n];
            lb32[n * 36 + cp] = pack_bf16(x0, x1);
        }
    }
    __syncthreads();

    const int lane = tid & 63;
    const int w    = tid >> 6;
    const int m    = lane & 15;
    const int q    = lane >> 4;
    const int n    = w * 16 + m;

    const bf16x8_t b0 = *(const bf16x8_t*)&lds_b[n * 72 + q * 8];
    const bf16x8_t b1 = *(const bf16x8_t*)&lds_b[n * 72 + q * 8 + 32];

    const size_t rowbase = ((size_t)(b * NDIM + n0 + n)) * 32;
    #pragma unroll
    for (int t = 0; t < 8; ++t) {
        const short* ap = &lds_a[(t * 16 + m) * 72 + q * 8];
        bf16x8_t a0 = *(const bf16x8_t*)ap;
        bf16x8_t a1 = *(const bf16x8_t*)(ap + 32);
        f32x4_t acc = {0.f, 0.f, 0.f, 0.f};
        acc = __builtin_amdgcn_mfma_f32_16x16x32_bf16(a0, b0, acc, 0, 0, 0);
        acc = __builtin_amdgcn_mfma_f32_16x16x32_bf16(a1, b1, acc, 0, 0, 0);
        unsigned* dst = (t < 4) ? y1p : y2p;
        uint2 pk = { pack_bf16(acc[0], acc[1]), pack_bf16(acc[2], acc[3]) };
        *(uint2*)&dst[rowbase + (t & 3) * 8 + q * 2] = pk;
    }
}

// ---------------- Kernel 2: gather, vector-idx + bpermute broadcast ----------------
// 2048 blocks x 256, XCD-pinned batches. 32 outstanding gathers/wave (R0 bursts).
__global__ __launch_bounds__(256, 4) void gather_kernel(
    const unsigned* __restrict__ y1p,        // (B,N,32) bf16-pairs
    const unsigned* __restrict__ y2p,
    const int* __restrict__ ei,              // (B, N, 16)
    const float* __restrict__ gamma,
    unsigned* __restrict__ hselp,            // (B,N,32) bf16-pairs
    float* __restrict__ statsN)              // (32,128)
{
    const int tid  = threadIdx.x;
    const int w    = __builtin_amdgcn_readfirstlane(tid >> 6);
    const int lane = tid & 63;
    const int half = lane >> 5;
    const int c2   = lane & 31;
    const int g    = blockIdx.x;
    const int xcd  = g & 7;
    const int b    = xcd >> 1;
    const int row0 = b * NDIM + (xcd & 1) * 8192 + (g >> 3) * 32 + w * 8;

    // 128 wave indices (rows row0..row0+7): 2 coalesced vector loads, issued first
    const int idx0 = ei[(size_t)row0 * KNB + lane];        // rows row0..row0+3
    const int idx1 = ei[(size_t)row0 * KNB + 64 + lane];   // rows row0+4..row0+7
    // y1 prefetch (consumed at the end of each p-phase)
    const unsigned y1A = y1p[(size_t)(row0 + 0 + half) * 32 + c2];
    const unsigned y1B = y1p[(size_t)(row0 + 2 + half) * 32 + c2];
    const unsigned y1C = y1p[(size_t)(row0 + 4 + half) * 32 + c2];
    const unsigned y1D = y1p[(size_t)(row0 + 6 + half) * 32 + c2];

    const unsigned sgn0 = (gamma[2 * c2]     >= 0.0f) ? 0x80000000u : 0u;
    const unsigned sgn1 = (gamma[2 * c2 + 1] >= 0.0f) ? 0x80000000u : 0u;
    const char* y2base = (const char*)y2p + (size_t)b * NDIM * 128;
    const unsigned coff = (unsigned)(c2 << 2);
    const int hb = half << 6;     // byte addr of this lane's source-lane base

    f32x2_t ssum = {0.f, 0.f};
    f32x2_t ssq  = {0.f, 0.f};

    #pragma unroll
    for (int t = 0; t < 2; ++t) {
        const int srci = t ? idx1 : idx0;
        const int ra = row0 + t * 4;         // pair0: rows ra, ra+1
        const int rb = ra + 2;               // pair1: rows rb, rb+1
        const unsigned y1u0 = t ? y1C : y1A;
        const unsigned y1u1 = t ? y1D : y1B;

        unsigned u0[KNB], u1[KNB];
        #pragma unroll
        for (int k = 0; k < KNB; ++k) {
            // row (ra+half)'s index k lives in lane half*16+k of srci
            int j = __builtin_amdgcn_ds_bpermute(hb + 4 * k, srci);
            u0[k] = *(const unsigned*)(y2base + ((((unsigned)j) << 7) + coff));
        }
        #pragma unroll
        for (int k = 0; k < KNB; ++k) {
            // row (rb+half)'s index k lives in lane 32+half*16+k
            int j = __builtin_amdgcn_ds_bpermute(128 + hb + 4 * k, srci);
            u1[k] = *(const unsigned*)(y2base + ((((unsigned)j) << 7) + coff));
        }

        #pragma unroll 2
        for (int p = 0; p < 2; ++p) {
            const unsigned* u = (p == 0) ? u0 : u1;
            const unsigned y1u = (p == 0) ? y1u0 : y1u1;
            const int rw = ((p == 0) ? ra : rb) + half;

            f32x2_t s2 = {0.f, 0.f};
            f32x2_t q2 = {0.f, 0.f};
            float M0 = -3.402823e38f, M1 = -3.402823e38f;
            #pragma unroll
            for (int k = 0; k < KNB; k += 2) {
                unsigned lo0 = u[k] << 16,     hi0 = u[k] & 0xffff0000u;
                unsigned lo1 = u[k + 1] << 16, hi1 = u[k + 1] & 0xffff0000u;
                f32x2_t v0 = { __uint_as_float(lo0), __uint_as_float(hi0) };
                f32x2_t v1 = { __uint_as_float(lo1), __uint_as_float(hi1) };
                s2 += v0;                                          // v_pk_add_f32
                q2 = __builtin_elementwise_fma(v0, v0, q2);        // v_pk_fma_f32
                s2 += v1;
                q2 = __builtin_elementwise_fma(v1, v1, q2);
                M0 = fmaxf(fmaxf(M0, __uint_as_float(lo0 ^ sgn0)),
                           __uint_as_float(lo1 ^ sgn0));           // v_max3_f32
                M1 = fmaxf(fmaxf(M1, __uint_as_float(hi0 ^ sgn1)),
                           __uint_as_float(hi1 ^ sgn1));
            }
            const f32x2_t y1v = { __uint_as_float(y1u << 16),
                                  __uint_as_float(y1u & 0xffff0000u) };
            const float h0 = y1v.x - __uint_as_float(__float_as_uint(M0) ^ sgn0);
            const float h1 = y1v.y - __uint_as_float(__float_as_uint(M1) ^ sgn1);
            hselp[(size_t)rw * 32 + c2] = pack_bf16(h0, h1);
            ssum += (f32x2_t){16.f, 16.f} * y1v - s2;
            ssq  += __builtin_elementwise_fma(
                        __builtin_elementwise_fma((f32x2_t){-2.f, -2.f}, s2,
                                                  (f32x2_t){16.f, 16.f} * y1v),
                        y1v, q2);
        }
    }

    __shared__ float rs[8][64];
    __shared__ float rq[8][64];
    rs[w * 2 + half][c2 * 2]     = ssum.x;
    rs[w * 2 + half][c2 * 2 + 1] = ssum.y;
    rq[w * 2 + half][c2 * 2]     = ssq.x;
    rq[w * 2 + half][c2 * 2 + 1] = ssq.y;
    __syncthreads();
    if (tid < 128) {
        const int c = tid & 63;
        float v = 0.f;
        if (tid < 64) { for (int r = 0; r < 8; ++r) v += rs[r][c]; }
        else          { for (int r = 0; r < 8; ++r) v += rq[r][c]; }
        atomicAdd(&statsN[(g & 31) * 128 + tid], v);   // striped: ~64 adds/line
    }
}

// ---------------- Kernel 3: reduce-in-prologue + affine + leaky + transpose ----------------
__global__ __launch_bounds__(256) void out_kernel(
    const unsigned* __restrict__ hselp,      // (B,N,32) bf16-pairs
    const float* __restrict__ statsN,        // (32,128)
    const float* __restrict__ gamma,
    const float* __restrict__ beta,
    float* __restrict__ out)                 // (B, 64, N)
{
    __shared__ float tile[64 * 65];
    __shared__ float colsum[128];
    __shared__ float sc[64], bi[64];
    const int tid = threadIdx.x;

    if (tid < 128) {
        float v = 0.f;
        #pragma unroll
        for (int i = 0; i < 32; ++i) v += statsN[i * 128 + tid];
        colsum[tid] = v;
    }
    __syncthreads();
    if (tid < 64) {
        float mean = colsum[tid] * (1.0f / BNK_F);
        float var  = colsum[64 + tid] * (1.0f / BNK_F) - mean * mean;
        float s    = gamma[tid] * rsqrtf(var + 1e-5f);
        sc[tid] = s;
        bi[tid] = beta[tid] - mean * s;
    }
    __syncthreads();

    const int b  = blockIdx.x >> 8;
    const int n0 = (blockIdx.x & 255) << 6;
    const size_t bn0 = (size_t)b * NDIM + n0;
    const int c4 = tid & 15;

    for (int r = tid >> 4; r < 64; r += 16) {
        uint2 u = *(const uint2*)&hselp[(bn0 + r) * 32 + c4 * 2];
        float v0 = fmaf(sc[4 * c4],     __uint_as_float(u.x << 16),         bi[4 * c4]);
        float v1 = fmaf(sc[4 * c4 + 1], __uint_as_float(u.x & 0xffff0000u), bi[4 * c4 + 1]);
        float v2 = fmaf(sc[4 * c4 + 2], __uint_as_float(u.y << 16),         bi[4 * c4 + 2]);
        float v3 = fmaf(sc[4 * c4 + 3], __uint_as_float(u.y & 0xffff0000u), bi[4 * c4 + 3]);
        v0 = (v0 >= 0.f) ? v0 : 0.2f * v0;
        v1 = (v1 >= 0.f) ? v1 : 0.2f * v1;
        v2 = (v2 >= 0.f) ? v2 : 0.2f * v2;
        v3 = (v3 >= 0.f) ? v3 : 0.2f * v3;
        tile[r * 65 + 4 * c4]     = v0;
        tile[r * 65 + 4 * c4 + 1] = v1;
        tile[r * 65 + 4 * c4 + 2] = v2;
        tile[r * 65 + 4 * c4 + 3] = v3;
    }
    __syncthreads();
    const int ln = tid & 15;
    for (int o = tid >> 4; o < 64; o += 16) {
        f32x4_t v;
        v[0] = tile[(ln * 4 + 0) * 65 + o];
        v[1] = tile[(ln * 4 + 1) * 65 + o];
        v[2] = tile[(ln * 4 + 2) * 65 + o];
        v[3] = tile[(ln * 4 + 3) * 65 + o];
        *(f32x4_t*)&out[((size_t)(b * 64 + o) << 14) + n0 + ln * 4] = v;
    }
}

extern "C" void kernel_launch(void* const* d_in, const int* in_sizes, int n_in,
                              void* d_out, int out_size, void* d_ws, size_t ws_size,
                              hipStream_t stream) {
    const float* x     = (const float*)d_in[0];
    const int*   ei    = (const int*)d_in[1];
    const float* W     = (const float*)d_in[2];
    const float* gamma = (const float*)d_in[3];
    const float* beta  = (const float*)d_in[4];
    float* out = (float*)d_out;

    char* ws = (char*)d_ws;
    unsigned* y1p    = (unsigned*)(ws);                       // 8 MiB (bf16 pairs)
    unsigned* y2p    = (unsigned*)(ws + 8388608);             // 8 MiB
    unsigned* hselp  = (unsigned*)(ws + 16777216);            // 8 MiB
    float*    statsN = (float*)(ws + 25165824);               // 16 KiB (32x128)

    gemm_mfma_kernel <<<dim3(1024), dim3(256), 0, stream>>>(x, W, y1p, y2p, statsN);
    gather_kernel    <<<dim3(2048), dim3(256), 0, stream>>>(y1p, y2p, ei, gamma, hselp, statsN);
    out_kernel       <<<dim3(1024), dim3(256), 0, stream>>>(hselp, statsN, gamma, beta, out);
}